// Round 4
// baseline (2209.109 us; speedup 1.0000x reference)
//
#include <hip/hip_runtime.h>

#define NN 128
#define NITER 300
#define NPASS 2   // 64-way tau search: bracket width /65 per pass -> ~1e-3 after 2;
                  // active-set boundary error ~1e-3 << 2e-2 threshold (ref re-derives
                  // tau from active set, so only boundary coords can differ)

// ---- DPP wave-64 cross-lane helpers (used sparingly now) ----
template<int CTRL>
__device__ __forceinline__ float dpp0(float x) {  // invalid lanes contribute 0
  return __int_as_float(__builtin_amdgcn_update_dpp(0, __float_as_int(x), CTRL, 0xF, 0xF, true));
}
template<int CTRL>
__device__ __forceinline__ float dppS(float x) {  // invalid lanes keep self
  int xi = __float_as_int(x);
  return __int_as_float(__builtin_amdgcn_update_dpp(xi, xi, CTRL, 0xF, 0xF, false));
}
__device__ __forceinline__ float bcast63(float x) {
  return __int_as_float(__builtin_amdgcn_readlane(__float_as_int(x), 63));
}
__device__ __forceinline__ float rlane(float x, int l) {   // l literal
  return __int_as_float(__builtin_amdgcn_readlane(__float_as_int(x), l));
}
__device__ __forceinline__ float wsum(float x) {
  x += dpp0<0x111>(x); x += dpp0<0x112>(x); x += dpp0<0x114>(x);
  x += dpp0<0x118>(x); x += dpp0<0x142>(x); x += dpp0<0x143>(x);
  return bcast63(x);
}
__device__ __forceinline__ void wsum2(float& x, float& y) {  // two interleaved chains
  float a = x, b = y;
  a += dpp0<0x111>(a); b += dpp0<0x111>(b);
  a += dpp0<0x112>(a); b += dpp0<0x112>(b);
  a += dpp0<0x114>(a); b += dpp0<0x114>(b);
  a += dpp0<0x118>(a); b += dpp0<0x118>(b);
  a += dpp0<0x142>(a); b += dpp0<0x142>(b);
  a += dpp0<0x143>(a); b += dpp0<0x143>(b);
  x = bcast63(a); y = bcast63(b);
}
__device__ __forceinline__ void wminmax(float& mn, float& mx) {  // interleaved
  mn = fminf(mn, dppS<0x111>(mn)); mx = fmaxf(mx, dppS<0x111>(mx));
  mn = fminf(mn, dppS<0x112>(mn)); mx = fmaxf(mx, dppS<0x112>(mx));
  mn = fminf(mn, dppS<0x114>(mn)); mx = fmaxf(mx, dppS<0x114>(mx));
  mn = fminf(mn, dppS<0x118>(mn)); mx = fmaxf(mx, dppS<0x118>(mx));
  mn = fminf(mn, dppS<0x142>(mn)); mx = fmaxf(mx, dppS<0x142>(mx));
  mn = fminf(mn, dppS<0x143>(mn)); mx = fmaxf(mx, dppS<0x143>(mx));
  mn = bcast63(mn); mx = bcast63(mx);
}

// 512 threads: row = t&127, col-quarter seg = t>>7; acc[32] per thread
// (lands in AGPRs per R3 — no scratch spill). No waves_per_eu pin: let the
// allocator choose; total regs ~68 may allow 3 blocks/CU.
__launch_bounds__(512)
__global__ void markowitz_kernel(const float* __restrict__ rets,
                                 const float* __restrict__ cov,
                                 const float* __restrict__ gam,
                                 const float* __restrict__ alp,
                                 float* __restrict__ out)
{
  __shared__ float yL[NN];
  __shared__ float wLs[NN];
  __shared__ float pL[4][NN];
  __shared__ __align__(16) float vLs[NN];
  __shared__ float red[8];

  const int b    = blockIdx.x;
  const int t    = threadIdx.x;
  const int lane = t & 63;
  const int wid  = t >> 6;          // 0..7
  const int row  = t & 127;         // this thread's Q row
  const int seg  = t >> 7;          // col quarter 0..3
  const int cl   = lane & 31;

  const float g   = gam[b];
  const float g2  = g * g;
  const float aab = fabsf(alp[b]);
  const float* cb = cov + (size_t)b * (NN * NN);

  // ---------- build: acc[u] = (C^T C)[row][32*seg+u] ----------
  float acc[32];
  #pragma unroll
  for (int u = 0; u < 32; ++u) acc[u] = 0.f;

  const float* ap = cb + row;             // C[k][row]
  const float* bp = cb + seg * 32 + cl;   // C[k][32*seg + cl]
  #pragma unroll 2
  for (int k = 0; k < NN; ++k) {
    float a  = ap[(size_t)k * NN];
    float bb = bp[(size_t)k * NN];
    #pragma unroll
    for (int u = 0; u < 32; ++u)
      acc[u] = fmaf(a, rlane(bb, u), acc[u]);
  }

  // finish Q = g2*C^TC + aab*I; block-wide Frobenius^2
  float ss = 0.f;
  #pragma unroll
  for (int u = 0; u < 32; ++u) {
    float q = g2 * acc[u];
    if (seg * 32 + u == row) q += aab;
    acc[u] = q;
    ss = fmaf(q, q, ss);
  }
  float ssw = wsum(ss);
  if (lane == 0) red[wid] = ssw;
  __syncthreads();
  const float S = ((red[0] + red[1]) + (red[2] + red[3]))
                + ((red[4] + red[5]) + (red[6] + red[7]));
  const float step = 0.5f / sqrtf(S);     // 1 / (2*||Q||_F)
  const float sc   = 2.f * step;
  #pragma unroll
  for (int u = 0; u < 32; ++u) acc[u] *= sc;   // acc = 2*step*Q

  const float r2a = step * rets[b * NN + lane];
  const float r2b = step * rets[b * NN + 64 + lane];

  if (t < NN) { yL[t] = 1.f / 128.f; wLs[t] = 1.f / 128.f; }
  __syncthreads();

  // ---------- FISTA ----------
  float t_f = 1.f;
  const int ownbase = ((b >> 8) * 2) & 7;  // co-resident blocks -> owners on distinct SIMDs

  for (int it = 0; it < NITER; ++it) {
    // matvec partial: pL[seg][row] = (2 step Q)[row][32seg..] . y[32seg..]
    float yv = yL[seg * 32 + cl];
    float p0 = 0.f, p1 = 0.f, p2 = 0.f, p3 = 0.f;
    #pragma unroll
    for (int u = 0; u < 32; u += 4) {
      p0 = fmaf(acc[u + 0], rlane(yv, u + 0), p0);
      p1 = fmaf(acc[u + 1], rlane(yv, u + 1), p1);
      p2 = fmaf(acc[u + 2], rlane(yv, u + 2), p2);
      p3 = fmaf(acc[u + 3], rlane(yv, u + 3), p3);
    }
    pL[seg][row] = (p0 + p1) + (p2 + p3);
    __syncthreads();

    if (wid == ((it + ownbase) & 7)) {
      // owner wave: v = y - step*grad (2 coords/lane), stash v in LDS
      float y0 = yL[lane],      y1 = yL[64 + lane];
      float q0 = (pL[0][lane] + pL[1][lane]) + (pL[2][lane] + pL[3][lane]);
      float q1 = (pL[0][64 + lane] + pL[1][64 + lane])
               + (pL[2][64 + lane] + pL[3][64 + lane]);
      float v0 = y0 - q0 + r2a;
      float v1 = y1 - q1 + r2b;
      vLs[lane] = v0; vLs[64 + lane] = v1;   // same-wave write->read, waitcnt only

      float mn = fminf(v0, v1), mx = fmaxf(v0, v1);
      wminmax(mn, mx);
      float lo = mn - 1.0f;
      float W  = mx - lo;

      // 64-way parallel tau search: lane l evaluates s(lo + (l+1)h)
      #pragma unroll 1
      for (int pass = 0; pass < NPASS; ++pass) {
        float h   = W * (1.f / 65.f);
        float tau = fmaf((float)(lane + 1), h, lo);
        float s0 = 0.f, s1 = 0.f, s2 = 0.f, s3 = 0.f;
        #pragma unroll
        for (int j = 0; j < 32; ++j) {       // wave-uniform b128 broadcasts
          float4 vv = *(const float4*)(vLs + 4 * j);
          s0 += __builtin_amdgcn_fmed3f(vv.x - tau, 0.f, 1.f);
          s1 += __builtin_amdgcn_fmed3f(vv.y - tau, 0.f, 1.f);
          s2 += __builtin_amdgcn_fmed3f(vv.z - tau, 0.f, 1.f);
          s3 += __builtin_amdgcn_fmed3f(vv.w - tau, 0.f, 1.f);
        }
        float s = (s0 + s1) + (s2 + s3);
        unsigned long long m = __ballot(s > 1.f);  // monotone -> prefix mask
        float cnt = (float)__popcll(m);
        lo = fmaf(cnt, h, lo);
        W  = h;
      }
      float tau0 = lo + 0.5f * W;

      // exact tau on the (fixed) active set, then w
      float z0 = v0 - tau0, z1 = v1 - tau0;
      bool f0 = (z0 > 0.f) && (z0 < 1.0f);
      bool f1 = (z1 > 0.f) && (z1 < 1.0f);
      bool cap0 = (z0 >= 1.0f), cap1 = (z1 >= 1.0f);
      float sfv = (f0 ? v0 : 0.f) + (f1 ? v1 : 0.f);
      float cnt = (f0 ? 1.f : 0.f) + (f1 ? 1.f : 0.f)
                + 1024.f * ((cap0 ? 1.f : 0.f) + (cap1 ? 1.f : 0.f));
      wsum2(sfv, cnt);
      float nu    = floorf(cnt * (1.f / 1024.f));
      float nfree = fmaxf(cnt - 1024.f * nu, 1.f);
      float tauf  = (sfv + nu - 1.f) / nfree;     // mw = 1
      float w0 = f0 ? (v0 - tauf) : (cap0 ? 1.0f : 0.f);
      float w1 = f1 ? (v1 - tauf) : (cap1 ? 1.0f : 0.f);

      float tn   = 0.5f * (1.f + sqrtf(1.f + 4.f * t_f * t_f));
      float coef = (t_f - 1.f) / tn;
      float wp0 = wLs[lane], wp1 = wLs[64 + lane];
      yL[lane]       = w0 + coef * (w0 - wp0);
      yL[64 + lane]  = w1 + coef * (w1 - wp1);
      wLs[lane] = w0;  wLs[64 + lane] = w1;
    }
    t_f = 0.5f * (1.f + sqrtf(1.f + 4.f * t_f * t_f));  // all waves track t
    __syncthreads();
  }

  if (t < NN) out[(size_t)b * NN + t] = wLs[t];
}

extern "C" void kernel_launch(void* const* d_in, const int* in_sizes, int n_in,
                              void* d_out, int out_size, void* d_ws, size_t ws_size,
                              hipStream_t stream) {
  (void)n_in; (void)d_ws; (void)ws_size; (void)out_size;
  const float* rets = (const float*)d_in[0];
  const float* cov  = (const float*)d_in[1];
  const float* gam  = (const float*)d_in[2];
  const float* alp  = (const float*)d_in[3];
  float* out = (float*)d_out;
  const int B = in_sizes[0] / NN;   // 1024
  markowitz_kernel<<<B, 512, 0, stream>>>(rets, cov, gam, alp, out);
}

// Round 5
// 873.385 us; speedup vs baseline: 2.5294x; 2.5294x over previous
//
#include <hip/hip_runtime.h>

#define NN 128
#define NITER 300
#define NSTEP 12   // safeguarded-Newton (bracket-clamped) on piecewise-linear s(tau);
                   // R2/R3 passed with 14 (absmax ~1e-4), R4 passed with far coarser search

// ---- DPP wave-64 cross-lane helpers ----
template<int CTRL>
__device__ __forceinline__ float dpp0(float x) {  // invalid lanes contribute 0
  return __int_as_float(__builtin_amdgcn_update_dpp(0, __float_as_int(x), CTRL, 0xF, 0xF, true));
}
template<int CTRL>
__device__ __forceinline__ float dppS(float x) {  // invalid lanes keep self
  int xi = __float_as_int(x);
  return __int_as_float(__builtin_amdgcn_update_dpp(xi, xi, CTRL, 0xF, 0xF, false));
}
__device__ __forceinline__ float bcast63(float x) {
  return __int_as_float(__builtin_amdgcn_readlane(__float_as_int(x), 63));
}
__device__ __forceinline__ float rlane(float x, int l) {   // l literal after unroll
  return __int_as_float(__builtin_amdgcn_readlane(__float_as_int(x), l));
}
__device__ __forceinline__ float wsum(float x) {
  x += dpp0<0x111>(x); x += dpp0<0x112>(x); x += dpp0<0x114>(x);
  x += dpp0<0x118>(x); x += dpp0<0x142>(x); x += dpp0<0x143>(x);
  return bcast63(x);
}
__device__ __forceinline__ void wsum2(float& x, float& y) {  // two interleaved chains
  float a = x, b = y;
  a += dpp0<0x111>(a); b += dpp0<0x111>(b);
  a += dpp0<0x112>(a); b += dpp0<0x112>(b);
  a += dpp0<0x114>(a); b += dpp0<0x114>(b);
  a += dpp0<0x118>(a); b += dpp0<0x118>(b);
  a += dpp0<0x142>(a); b += dpp0<0x142>(b);
  a += dpp0<0x143>(a); b += dpp0<0x143>(b);
  x = bcast63(a); y = bcast63(b);
}
__device__ __forceinline__ void wminmax(float& mn, float& mx) {  // interleaved
  mn = fminf(mn, dppS<0x111>(mn)); mx = fmaxf(mx, dppS<0x111>(mx));
  mn = fminf(mn, dppS<0x112>(mn)); mx = fmaxf(mx, dppS<0x112>(mx));
  mn = fminf(mn, dppS<0x114>(mn)); mx = fmaxf(mx, dppS<0x114>(mx));
  mn = fminf(mn, dppS<0x118>(mn)); mx = fmaxf(mx, dppS<0x118>(mx));
  mn = fminf(mn, dppS<0x142>(mn)); mx = fmaxf(mx, dppS<0x142>(mx));
  mn = fminf(mn, dppS<0x143>(mn)); mx = fmaxf(mx, dppS<0x143>(mx));
  mn = bcast63(mn); mx = bcast63(mx);
}

// ONE WAVE PER SAMPLE. 1024 waves = 1 wave/SIMD device-wide. Q (128x128) lives
// in-wave: lane owns rows {lane, lane+64} -> accA/accB[128] = 256 VGPRs.
// No LDS, no __syncthreads anywhere. launch_bounds(64,1) -> 512-VGPR budget.
__launch_bounds__(64, 1)
__global__ void markowitz_kernel(const float* __restrict__ rets,
                                 const float* __restrict__ cov,
                                 const float* __restrict__ gam,
                                 const float* __restrict__ alp,
                                 float* __restrict__ out)
{
  const int b    = blockIdx.x;
  const int lane = threadIdx.x;          // block = exactly one wave (64)

  const float g   = gam[b];
  const float g2  = g * g;
  const float aab = fabsf(alp[b]);
  const float* cb = cov + (size_t)b * (NN * NN);

  // ---------- build Q = g2*C^T C + aab*I (rows lane / lane+64) ----------
  float accA[NN], accB[NN];
  #pragma unroll
  for (int u = 0; u < NN; ++u) { accA[u] = 0.f; accB[u] = 0.f; }

  const float* ap0 = cb + lane;
  const float* ap1 = cb + lane + 64;
  #pragma unroll 2
  for (int k = 0; k < NN; ++k) {
    float a0 = ap0[(size_t)k * NN];      // C[k][lane]      (coalesced)
    float a1 = ap1[(size_t)k * NN];      // C[k][lane+64]
    #pragma unroll
    for (int u = 0; u < 64; ++u) {
      float s0 = rlane(a0, u);           // C[k][u]
      float s1 = rlane(a1, u);           // C[k][64+u]
      accA[u]      = fmaf(a0, s0, accA[u]);
      accA[64 + u] = fmaf(a0, s1, accA[64 + u]);
      accB[u]      = fmaf(a1, s0, accB[u]);
      accB[64 + u] = fmaf(a1, s1, accB[64 + u]);
    }
  }

  // scale, diagonal, Frobenius^2 (4 partial chains)
  float ss0 = 0.f, ss1 = 0.f, ss2 = 0.f, ss3 = 0.f;
  #pragma unroll
  for (int u = 0; u < NN; ++u) {
    float qa = g2 * accA[u]; if (u == lane)      qa += aab;
    float qb = g2 * accB[u]; if (u == lane + 64) qb += aab;
    accA[u] = qa; accB[u] = qb;
    if (u & 1) { ss0 = fmaf(qa, qa, ss0); ss1 = fmaf(qb, qb, ss1); }
    else       { ss2 = fmaf(qa, qa, ss2); ss3 = fmaf(qb, qb, ss3); }
  }
  const float S    = wsum((ss0 + ss2) + (ss1 + ss3));
  const float step = 0.5f / sqrtf(S);    // 1/(2||Q||_F)
  const float sc   = 2.f * step;
  #pragma unroll
  for (int u = 0; u < NN; ++u) { accA[u] *= sc; accB[u] *= sc; }  // acc = 2*step*Q

  const float r2a = step * rets[b * NN + lane];
  const float r2b = step * rets[b * NN + 64 + lane];

  // ---------- FISTA, fully in-wave ----------
  float y0 = 1.f / 128.f, y1 = 1.f / 128.f;   // y coords (lane, lane+64)
  float w0p = y0, w1p = y1;                   // w_prev
  float t_f = 1.f;

  #pragma unroll 1
  for (int it = 0; it < NITER; ++it) {
    // matvec: 4 independent fma chains, y broadcast via readlane
    float pA0 = 0.f, pA1 = 0.f, pB0 = 0.f, pB1 = 0.f;
    #pragma unroll
    for (int u = 0; u < 64; ++u) {
      float t0 = rlane(y0, u);
      float t1 = rlane(y1, u);
      pA0 = fmaf(accA[u],      t0, pA0);
      pA1 = fmaf(accA[64 + u], t1, pA1);
      pB0 = fmaf(accB[u],      t0, pB0);
      pB1 = fmaf(accB[64 + u], t1, pB1);
    }
    float v0 = y0 - (pA0 + pA1) + r2a;   // v = y - step*grad
    float v1 = y1 - (pB0 + pB1) + r2b;

    // projection onto {sum w = 1, 0<=w<=1}
    float mn = fminf(v0, v1), mx = fmaxf(v0, v1);
    wminmax(mn, mx);
    float lo = mn - 1.0f, hi = mx;
    float tau = 0.5f * (lo + hi);
    #pragma unroll 1
    for (int s2 = 0; s2 < NSTEP; ++s2) {
      float z0 = v0 - tau, z1 = v1 - tau;
      float c0 = __builtin_amdgcn_fmed3f(z0, 0.f, 1.f);
      float c1 = __builtin_amdgcn_fmed3f(z1, 0.f, 1.f);
      float f0 = (c0 > 0.f && c0 < 1.f) ? 1.f : 0.f;
      float f1 = (c1 > 0.f && c1 < 1.f) ? 1.f : 0.f;
      float s = c0 + c1, nf = f0 + f1;
      wsum2(s, nf);
      bool gt = (s > 1.f);
      lo = gt ? tau : lo;
      hi = gt ? hi : tau;
      float tn = fmaf(s - 1.f, __builtin_amdgcn_rcpf(fmaxf(nf, 1.f)), tau);
      tau = (tn > lo && tn < hi) ? tn : 0.5f * (lo + hi);
    }
    float tau0 = 0.5f * (lo + hi);
    float z0 = v0 - tau0, z1 = v1 - tau0;
    bool f0 = (z0 > 0.f) && (z0 < 1.0f);
    bool f1 = (z1 > 0.f) && (z1 < 1.0f);
    bool cap0 = (z0 >= 1.0f), cap1 = (z1 >= 1.0f);
    float sfv = (f0 ? v0 : 0.f) + (f1 ? v1 : 0.f);
    float cnt = (f0 ? 1.f : 0.f) + (f1 ? 1.f : 0.f)
              + 1024.f * ((cap0 ? 1.f : 0.f) + (cap1 ? 1.f : 0.f));
    wsum2(sfv, cnt);
    float nu    = floorf(cnt * (1.f / 1024.f));
    float nfree = fmaxf(cnt - 1024.f * nu, 1.f);
    float tauf  = (sfv + nu - 1.f) / nfree;        // exact tau on fixed active set
    float w0 = f0 ? (v0 - tauf) : (cap0 ? 1.0f : 0.f);
    float w1 = f1 ? (v1 - tauf) : (cap1 ? 1.0f : 0.f);

    // FISTA momentum
    float tn   = 0.5f * (1.f + sqrtf(1.f + 4.f * t_f * t_f));
    float coef = (t_f - 1.f) / tn;
    y0 = w0 + coef * (w0 - w0p);
    y1 = w1 + coef * (w1 - w1p);
    w0p = w0; w1p = w1;
    t_f = tn;
  }

  out[(size_t)b * NN + lane]      = w0p;
  out[(size_t)b * NN + 64 + lane] = w1p;
}

extern "C" void kernel_launch(void* const* d_in, const int* in_sizes, int n_in,
                              void* d_out, int out_size, void* d_ws, size_t ws_size,
                              hipStream_t stream) {
  (void)n_in; (void)d_ws; (void)ws_size; (void)out_size;
  const float* rets = (const float*)d_in[0];
  const float* cov  = (const float*)d_in[1];
  const float* gam  = (const float*)d_in[2];
  const float* alp  = (const float*)d_in[3];
  float* out = (float*)d_out;
  const int B = in_sizes[0] / NN;   // 1024 waves, one sample each
  markowitz_kernel<<<B, 64, 0, stream>>>(rets, cov, gam, alp, out);
}